// Round 3
// baseline (592.513 us; speedup 1.0000x reference)
//
#include <hip/hip_runtime.h>

// Problem: segment-mean of x[:,0] over sorted `batch` -> out[4096]
//   x:          (1e6, 128) f32   (d_in[0])  -- only column 0 used (stride-512B gather)
//   edge_index: (2, 1e6)   int   (d_in[1])  -- UNUSED
//   edge_attr:  (1e6, 16)  f32   (d_in[2])  -- UNUSED
//   batch:      (1e6,)     int   (d_in[3])  -- SORTED, values in [0, 4096)
//
// Design (R3): batch sorted => segment g is contiguous [lower_bound(g),
// lower_bound(g+1)). One 64-lane wave per graph: lanes 0/1 binary-search the
// two bounds (20 probes, L3-resident 4 MB batch), broadcast via shfl, then
// gather-reduce x[:,0] over the range (avg 244 elems -> ~4 loads/lane),
// butterfly shuffle-reduce, lane 0 writes out[g] = sum/count.
// No workspace, no atomics, single kernel launch. Empty segment -> 0/0 = NaN,
// matching the reference's sums/counts semantics.

#define N_GRAPHS 4096
#define D_FEAT   128

__global__ __launch_bounds__(64) void segmean_kernel(
        const float* __restrict__ x,
        const int*   __restrict__ batch,
        float* __restrict__ out,
        int n) {
    int g    = blockIdx.x;           // one wave per graph
    int lane = threadIdx.x;          // 0..63

    // lower_bound(target): lane 0 -> g, lanes 1..63 -> g+1 (redundant copies).
    int target = g + (lane != 0 ? 1 : 0);
    int lo = 0, hi = n;
    while (lo < hi) {
        int mid = (lo + hi) >> 1;
        if (batch[mid] < target) lo = mid + 1; else hi = mid;
    }
    int start = __shfl(lo, 0);
    int end   = __shfl(lo, 1);
    int count = end - start;

    // Gather-reduce the x column over [start, end), 64 lanes strided.
    float s = 0.0f;
    for (int i = start + lane; i < end; i += 64) {
        s += __builtin_nontemporal_load(&x[(size_t)i * D_FEAT]);
    }

    // Butterfly reduction across the wave.
    #pragma unroll
    for (int off = 32; off > 0; off >>= 1) {
        s += __shfl_xor(s, off);
    }

    if (lane == 0) {
        out[g] = s / (float)count;   // count==0 -> NaN, same as reference
    }
}

extern "C" void kernel_launch(void* const* d_in, const int* in_sizes, int n_in,
                              void* d_out, int out_size, void* d_ws, size_t ws_size,
                              hipStream_t stream) {
    const float* x     = (const float*)d_in[0];
    const int*   batch = (const int*)  d_in[3];
    int n_nodes = in_sizes[3];       // 1,000,000

    segmean_kernel<<<N_GRAPHS, 64, 0, stream>>>(
        x, batch, (float*)d_out, n_nodes);
}